// Round 6
// baseline (329.062 us; speedup 1.0000x reference)
//
#include <hip/hip_runtime.h>

// Problem shape (fixed by setup_inputs): inputs [B=32, T=4096, F=256] fp32.
constexpr int B_ = 32;
constexpr int T_ = 4096;
constexpr int F_ = 256;
constexpr int F4 = F_ / 4;
constexpr int CH = 64;                // chunks along T
constexpr int L_ = T_ / CH;           // 64 timesteps per chunk
constexpr int NBLK = B_ * CH;         // 2048 blocks -> 8 blocks/CU, 32 w/CU
constexpr float EPS_ = 1e-6f;

// Mapping: block = (b,chunk); thread tid owns f = tid and walks t.
// Per t the block touches a contiguous 1 KB; per thread a 4-B dword at 1-KB
// stride. A 16-deep prefetch batch = 16 VGPRs -> actually fits (rounds 0/1
// float4 batches needed 64 VGPRs and were silently serialized -> 1-2 TB/s).

// ---- ordered-uint encoding for float atomic min/max (handles any sign) ----
__device__ __forceinline__ unsigned f2ord(float f) {
    unsigned u = __float_as_uint(f);
    return (u & 0x80000000u) ? ~u : (u | 0x80000000u);
}
__device__ __forceinline__ float ord2f(unsigned u) {
    return (u & 0x80000000u) ? __uint_as_float(u ^ 0x80000000u)
                             : __uint_as_float(~u);
}
__device__ __forceinline__ float clamp01(float v) {
    return fminf(fmaxf(v, 0.0f), 1.0f);
}

__device__ __forceinline__ float pcen_elem(float xv, float av, float g,
                                           float inv_r, float bias,
                                           float bpow) {
    const float p = __builtin_exp2f(-g * __builtin_log2f(EPS_ + av));
    const float base = fmaf(xv, p, bias);              // >= bias > 0
    return __builtin_exp2f(inv_r * __builtin_log2f(base)) - bpow;
}

// ---------------------------------------------------------------------------
// Kernel A: chunk-local EMA with zero seed -> E[b][c][f].
// 16-deep independent dword prefetch; serial chain only on the fma side.
// ---------------------------------------------------------------------------
__global__ __launch_bounds__(256, 8) void ema_chunk_local(
        const float* __restrict__ x, const float* __restrict__ smooth,
        float* __restrict__ E, unsigned* __restrict__ mm) {
    const int bc = blockIdx.x;
    const int f  = threadIdx.x;
    if (bc == 0 && f == 0) {
        mm[0] = 0xFFFFFFFFu;  // ordered-min init (= +inf)
        mm[1] = 0x00000000u;  // ordered-max init (= -inf)
    }
    const float w = clamp01(smooth[0]);
    const float d = 1.0f - w;
    const float* xp = x + (size_t)bc * L_ * F_ + f;

    float a = 0.0f;
    for (int t0 = 0; t0 < L_; t0 += 16) {
        float v[16];
#pragma unroll
        for (int i = 0; i < 16; ++i) v[i] = xp[(size_t)(t0 + i) * F_];
#pragma unroll
        for (int i = 0; i < 16; ++i) a = fmaf(w, v[i], d * a);
    }
    E[(size_t)bc * F_ + f] = a;
}

// ---------------------------------------------------------------------------
// Kernel B: cross-chunk carry scan (serial over 64 chunks per b).
// In_0 = x[b,0,f]; In_c = d^L * In_{c-1} + E_{c-1}.  One wave per b.
// ---------------------------------------------------------------------------
__global__ __launch_bounds__(64) void ema_carry(
        const float* __restrict__ x, const float* __restrict__ smooth,
        const float* __restrict__ E, float* __restrict__ In) {
    const int b = blockIdx.x;
    const int lane = threadIdx.x;
    const float w = clamp01(smooth[0]);
    const float d = 1.0f - w;
    float dL = d;                    // d^64 via 6 squarings
    dL *= dL; dL *= dL; dL *= dL; dL *= dL; dL *= dL; dL *= dL;
    static_assert(L_ == 64, "dL squaring chain assumes L_ == 64");

    float4 cur = reinterpret_cast<const float4*>(x + (size_t)b * T_ * F_)[lane];
    for (int c0 = 0; c0 < CH; c0 += 8) {
        float4 e[8];
#pragma unroll
        for (int i = 0; i < 8; ++i)
            e[i] = reinterpret_cast<const float4*>(E)[
                       ((size_t)b * CH + c0 + i) * F4 + lane];
#pragma unroll
        for (int i = 0; i < 8; ++i) {
            reinterpret_cast<float4*>(In)[
                ((size_t)b * CH + c0 + i) * F4 + lane] = cur;
            cur.x = fmaf(dL, cur.x, e[i].x);
            cur.y = fmaf(dL, cur.y, e[i].y);
            cur.z = fmaf(dL, cur.z, e[i].z);
            cur.w = fmaf(dL, cur.w, e[i].w);
        }
    }
}

// ---------------------------------------------------------------------------
// Kernel C: seeded rescan + PCEN -> out (pre-norm) + global min/max.
// Same scalar-f mapping; 8-deep prefetch (stores ride the VMEM queue too).
// ---------------------------------------------------------------------------
__global__ __launch_bounds__(256, 8) void pcen_minmax_out(
        const float* __restrict__ x, const float* __restrict__ In,
        const float* __restrict__ gain, const float* __restrict__ bias_p,
        const float* __restrict__ root, const float* __restrict__ smooth,
        float* __restrict__ out, unsigned* __restrict__ mm) {
    __shared__ float red[2][4];
    const int bc = blockIdx.x;
    const int f  = threadIdx.x;
    const float w = clamp01(smooth[0]);
    const float d = 1.0f - w;
    const float g = fminf(gain[0], 1.0f);
    const float r = fmaxf(root[0], 1.0f);
    const float inv_r = 1.0f / r;
    const float bias = bias_p[0];
    const float bpow = __builtin_exp2f(inv_r * __builtin_log2f(bias));

    const float* xp = x + (size_t)bc * L_ * F_ + f;
    float* op = out + (size_t)bc * L_ * F_ + f;
    float a = In[(size_t)bc * F_ + f];

    float lmin = __builtin_inff(), lmax = -__builtin_inff();
    for (int t0 = 0; t0 < L_; t0 += 8) {
        float v[8];
#pragma unroll
        for (int i = 0; i < 8; ++i) v[i] = xp[(size_t)(t0 + i) * F_];
#pragma unroll
        for (int i = 0; i < 8; ++i) {
            a = fmaf(w, v[i], d * a);
            const float o = pcen_elem(v[i], a, g, inv_r, bias, bpow);
            lmin = fminf(lmin, o);
            lmax = fmaxf(lmax, o);
            op[(size_t)(t0 + i) * F_] = o;      // pre-norm out
        }
    }
    // 64-lane butterfly, then cross-wave LDS reduce, one atomic pair/block
#pragma unroll
    for (int off = 32; off > 0; off >>= 1) {
        lmin = fminf(lmin, __shfl_xor(lmin, off));
        lmax = fmaxf(lmax, __shfl_xor(lmax, off));
    }
    const int wid = threadIdx.x >> 6;
    if ((threadIdx.x & 63) == 0) { red[0][wid] = lmin; red[1][wid] = lmax; }
    __syncthreads();
    if (threadIdx.x == 0) {
        float bmin = red[0][0], bmax = red[1][0];
#pragma unroll
        for (int i = 1; i < 4; ++i) {
            bmin = fminf(bmin, red[0][i]);
            bmax = fmaxf(bmax, red[1][i]);
        }
        atomicMin(&mm[0], f2ord(bmin));
        atomicMax(&mm[1], f2ord(bmax));
    }
}

// ---------------------------------------------------------------------------
// Kernel D: in-place global min/max normalization (flat grid-stride sweep —
// proven ~6 TB/s pattern; do NOT block-chunk this).
// ---------------------------------------------------------------------------
__global__ __launch_bounds__(256) void norm_apply(
        float* __restrict__ out, const unsigned* __restrict__ mm, int n4) {
    const float mn = ord2f(mm[0]);
    const float mx = ord2f(mm[1]);
    const float s = 2.0f / (mx - mn);
    const float o = fmaf(-mn, s, -1.0f);
    float4* p = reinterpret_cast<float4*>(out);
    const int stride = gridDim.x * blockDim.x;
    for (int i = blockIdx.x * blockDim.x + threadIdx.x; i < n4; i += stride) {
        float4 v = p[i];
        v.x = fmaf(v.x, s, o);
        v.y = fmaf(v.y, s, o);
        v.z = fmaf(v.z, s, o);
        v.w = fmaf(v.w, s, o);
        p[i] = v;
    }
}

extern "C" void kernel_launch(void* const* d_in, const int* in_sizes, int n_in,
                              void* d_out, int out_size, void* d_ws, size_t ws_size,
                              hipStream_t stream) {
    const float* x      = (const float*)d_in[0];
    const float* gain   = (const float*)d_in[1];
    const float* bias   = (const float*)d_in[2];
    const float* root   = (const float*)d_in[3];
    const float* smooth = (const float*)d_in[4];
    float* out = (float*)d_out;

    // ws layout: E [B*CH*F] | In [B*CH*F] | mm[2]   (4 MiB + 8 B)
    float* E  = (float*)d_ws;
    float* In = E + (size_t)B_ * CH * F_;
    unsigned* mm = (unsigned*)(In + (size_t)B_ * CH * F_);

    ema_chunk_local<<<NBLK, 256, 0, stream>>>(x, smooth, E, mm);
    ema_carry<<<B_, 64, 0, stream>>>(x, smooth, E, In);
    pcen_minmax_out<<<NBLK, 256, 0, stream>>>(x, In, gain, bias, root, smooth,
                                              out, mm);
    norm_apply<<<2048, 256, 0, stream>>>(out, mm, (B_ * T_ * F_) / 4);
}